// Round 3
// baseline (229.382 us; speedup 1.0000x reference)
//
#include <hip/hip_runtime.h>
#include <hip/hip_bf16.h>

// GIN: 3x [agg = segment_sum(h[src], dst); r = h + agg; h = relu(r@Wa+ba)@Wb+bb]
// then mean over nodes @ Wout + bout -> [1,16]
//
// R14 (from R12 @ 199us; R13 coop mega-kernel FAILED - likely silent launch
// rejection, output never written). Multi-launch structure kept, with the
// coop-independent wins ported:
//  - 8 -> 6 launches: sort_offsets_a folded into S3/S4 (each recomputes
//    chunk-prefix / bucket-totals from gh in-block, ~1us aggregate);
//    final_kernel folded into gin L2 via last-block ticket (device-scope
//    atomicAdd, no spin -> safe without co-residency).
//  - weights pre-converted/transposed to bf16 once in S1 (6 extra blocks);
//    per-layer staging = 2 iters of uint4 copies (was 16 iters fp32+cvt).
//  - feature cvt re-granularized: 1024 grid-stride blocks (was 6251 tiny).
// Gather structure unchanged from R12 (LDS-staged keys, masked batch-8,
// dummy zero row, f32x2 packed acc).

#define NNODES 50000
#define NEDGES 800000
#define DDIM   64
#define DOUT   16

#define CHUNK  4096
#define NB1    196           // ceil(800000/4096) sort chunks
#define NBUCK  196           // ceil(50000/256), bucket = dst>>8
#define NB64   782           // ceil(50000/64) gin blocks
#define CVTB   1024          // feature-cvt blocks (grid-stride)

#define KCAP   1408          // staged edges/block (mean 1024, sigma~32; +12 sigma)

typedef unsigned int uint;
typedef unsigned short ushort;
typedef __attribute__((ext_vector_type(8))) short bf16x8;
typedef __attribute__((ext_vector_type(4))) float f32x4;
typedef __attribute__((ext_vector_type(2))) float f32x2;

#define LSTR 72   // LDS row stride in ushorts (144B rows, 16B-aligned)

// fp32 -> bf16 RNE (bit trick)
static __device__ __forceinline__ uint f2bf(float f) {
    uint u = __float_as_uint(f);
    return (u + 0x7fffu + ((u >> 16) & 1u)) >> 16;
}
static __device__ __forceinline__ float bf_lo(uint u) { return __uint_as_float(u << 16); }
static __device__ __forceinline__ float bf_hi(uint u) { return __uint_as_float(u & 0xffff0000u); }

#define ACC4(vv) do { f32x2 u_;                                   \
    u_.x = bf_lo((vv).x); u_.y = bf_hi((vv).x); c0 += u_;         \
    u_.x = bf_lo((vv).y); u_.y = bf_hi((vv).y); c1 += u_;         \
    u_.x = bf_lo((vv).z); u_.y = bf_hi((vv).z); c2 += u_;         \
    u_.x = bf_lo((vv).w); u_.y = bf_hi((vv).w); c3 += u_; } while (0)

// ---------------- S1: keypack+hist | feature cvt | weight cvt | misc zero ----------------

__global__ __launch_bounds__(256) void s1_kernel(const int* __restrict__ src,
                                                 const int* __restrict__ dst,
                                                 uint* __restrict__ key,
                                                 int* __restrict__ gh,
                                                 const float2* __restrict__ fin,
                                                 uint* __restrict__ hb0,
                                                 uint* __restrict__ hb1,
                                                 const float* __restrict__ Wa0,
                                                 const float* __restrict__ Wb0,
                                                 const float* __restrict__ Wa1,
                                                 const float* __restrict__ Wb1,
                                                 const float* __restrict__ Wa2,
                                                 const float* __restrict__ Wb2,
                                                 uint* __restrict__ wWT,
                                                 float* __restrict__ part,
                                                 int* __restrict__ ticket) {
    __shared__ int h[NBUCK];
    int blk = blockIdx.x;
    int t = threadIdx.x;
    if (blk < NB1) {
        for (int i = t; i < NBUCK; i += 256) h[i] = 0;
        __syncthreads();
        int base = blk * CHUNK;
        int end = base + CHUNK < NEDGES ? base + CHUNK : NEDGES;
        for (int i = base + t; i < end; i += 256) {
            int d = dst[i];
            key[i] = ((uint)d << 16) | (uint)src[i];
            atomicAdd(&h[d >> 8], 1);
        }
        __syncthreads();
        for (int i = t; i < NBUCK; i += 256) gh[blk * NBUCK + i] = h[i];
        return;
    }
    int m = blk - NB1;
    if (m < CVTB) {
        // feature cvt (fp32 -> packed bf16), includes dummy row NNODES (zeroed)
        for (int i = m * 256 + t; i < (NNODES + 1) * 32; i += CVTB * 256) {
            uint r = 0u;
            if (i < NNODES * 32) {
                float2 v = fin[i];
                r = f2bf(v.x) | (f2bf(v.y) << 16);
            }
            hb0[i] = r;
        }
        return;
    }
    m -= CVTB;
    if (m < 6) {
        // weight cvt+transpose: wWT[m] as ushort[nn*64 + k] = bf16(W[k][nn])
        const float* Wm = (m == 0) ? Wa0 : (m == 1) ? Wb0 : (m == 2) ? Wa1
                        : (m == 3) ? Wb1 : (m == 4) ? Wa2 : Wb2;
        for (int o = t; o < 2048; o += 256) {
            int nn = o >> 5, kk = o & 31;
            wWT[m * 2048 + o] = f2bf(Wm[(2 * kk) * 64 + nn]) |
                                (f2bf(Wm[(2 * kk + 1) * 64 + nn]) << 16);
        }
        return;
    }
    // misc zeroing block
    if (t < 64) part[t] = 0.f;
    if (t == 64) *ticket = 0;
    if (t >= 128 && t < 160) hb1[NNODES * 32 + (t - 128)] = 0u;   // hb1 dummy row
}

// ---------------- S3: partition into coarse buckets (offsets self-computed) ----------------

__global__ __launch_bounds__(256) void sort_scatter1_kernel(const uint* __restrict__ key,
                                                            const int* __restrict__ gh,
                                                            uint* __restrict__ out) {
    __shared__ int s[256];
    __shared__ int cur[NBUCK];
    int blk = blockIdx.x;
    int t = threadIdx.x;
    // own chunk-prefix + bucket totals from gh (coalesced row reads)
    int own = 0, total = 0;
    if (t < NBUCK) {
        for (int c = 0; c < NB1; c++) {
            int v = gh[c * NBUCK + t];
            own += (c < blk) ? v : 0;
            total += v;
        }
    }
    s[t] = (t < NBUCK) ? total : 0;
    __syncthreads();
    for (int off = 1; off < 256; off <<= 1) {
        int add = (t >= off) ? s[t - off] : 0;
        __syncthreads();
        s[t] += add;
        __syncthreads();
    }
    if (t < NBUCK) cur[t] = (s[t] - total) + own;   // bucket base + own offset
    __syncthreads();
    int base = blk * CHUNK;
    int end = base + CHUNK < NEDGES ? base + CHUNK : NEDGES;
    for (int j = base + t; j < end; j += 256) {
        uint k = key[j];
        int pos = atomicAdd(&cur[k >> 24], 1);   // k>>24 == dst>>8
        out[pos] = k;
    }
}

// ---------------- S4: per-bucket counting sort (bases self-computed); emits rowptr ----------------

__global__ __launch_bounds__(256) void sort_bucket_kernel(const uint* __restrict__ in,
                                                          const int* __restrict__ gh,
                                                          int* __restrict__ rowptr,
                                                          uint* __restrict__ out) {
    __shared__ int s[256];
    __shared__ int hh[256];
    __shared__ int cur[256];
    __shared__ int slo[2];
    int blk = blockIdx.x;
    int t = threadIdx.x;
    int total = 0;
    if (t < NBUCK) {
        for (int c = 0; c < NB1; c++) total += gh[c * NBUCK + t];
    }
    s[t] = (t < NBUCK) ? total : 0;
    __syncthreads();
    for (int off = 1; off < 256; off <<= 1) {
        int add = (t >= off) ? s[t - off] : 0;
        __syncthreads();
        s[t] += add;
        __syncthreads();
    }
    if (t == blk) { slo[0] = s[t] - total; slo[1] = s[t]; }
    hh[t] = 0;
    __syncthreads();
    int lo = slo[0], hi = slo[1];
    for (int i = lo + t; i < hi; i += 256)
        atomicAdd(&hh[(in[i] >> 16) & 255], 1);
    __syncthreads();
    int hv = hh[t];
    s[t] = hv;
    __syncthreads();
    for (int off = 1; off < 256; off <<= 1) {
        int add = (t >= off) ? s[t - off] : 0;
        __syncthreads();
        s[t] += add;
        __syncthreads();
    }
    cur[t] = lo + s[t] - hv;   // exclusive scan + bucket base
    __syncthreads();
    int node = (blk << 8) + t;
    if (node < NNODES) rowptr[node] = cur[t];
    if (blk == NBUCK - 1 && t == 0) rowptr[NNODES] = NEDGES;
    __syncthreads();   // rowptr reads of cur[] before scatter mutates it
    for (int i = lo + t; i < hi; i += 256) {
        uint k = in[i];
        int pos = atomicAdd(&cur[(k >> 16) & 255], 1);
        out[pos] = k;
    }
}

// ---------------- fused GIN layer ----------------
// 64 nodes/block, 4 waves; wave w owns rows 16w..16w+15 end-to-end. Edge src
// indices + rowptr staged in LDS; masked batch-8 gather (dummy zero row
// NNODES); weights staged from pre-converted bf16 wWT (uint4 copies).
// part != nullptr (layer 3): fp32 colsums -> atomicAdd part; LAST block
// (device ticket) computes the final linear into out.

__global__ __launch_bounds__(256) void gin_layer_kernel(const uint4* __restrict__ h128,
                                                        const int* __restrict__ rowptr,
                                                        const uint* __restrict__ skey,
                                                        const uint4* __restrict__ wa4,
                                                        const uint4* __restrict__ wb4,
                                                        const float* __restrict__ ba,
                                                        const float* __restrict__ bb,
                                                        uint4* __restrict__ out128,
                                                        float* __restrict__ part,
                                                        int* __restrict__ ticket,
                                                        const float* __restrict__ Wout,
                                                        const float* __restrict__ bout,
                                                        float* __restrict__ out, int n) {
    __shared__ ushort sW1[64 * LSTR];   // Wa^T bf16 [n][k]
    __shared__ ushort sW2[64 * LSTR];   // Wb^T bf16 [n][k]
    __shared__ ushort sX[64 * LSTR];    // r tile -> hidden tile -> output staging
    __shared__ float sba[64], sbb[64];
    __shared__ ushort sSrc[KCAP + 8];   // staged src indices (+8 slack for masked reads)
    __shared__ int sRP[65];             // staged rowptr[node0..node0+64]
    __shared__ float pool[256];
    __shared__ int lastFlag;

    int t = threadIdx.x;
    int node0 = blockIdx.x * 64;

    for (int i = t; i < 512; i += 256) {
        int nn = i >> 3, k8 = i & 7;
        *(uint4*)&sW1[nn * LSTR + k8 * 8] = wa4[nn * 8 + k8];
        *(uint4*)&sW2[nn * LSTR + k8 * 8] = wb4[nn * 8 + k8];
    }
    if (t < 64) { sba[t] = ba[t]; sbb[t] = bb[t]; }
    if (t < 65) {
        int idx = node0 + t;
        sRP[t] = rowptr[idx < n ? idx : n];
    }
    if (blockIdx.x == 0 && t < 8) {     // zero dummy row of this layer's output
        uint4 z; z.x = 0; z.y = 0; z.z = 0; z.w = 0;
        out128[(size_t)NNODES * 8 + t] = z;
    }
    int eBase = rowptr[node0];
    int vEnd = node0 + 64 < n ? node0 + 64 : n;
    int nE = rowptr[vEnd] - eBase;
    int nS = nE < KCAP ? nE : KCAP;
    for (int i = t; i < nS; i += 256) sSrc[i] = (ushort)skey[eBase + i];
    __syncthreads();   // the only barrier: weights/keys/rowptr visible

    int lane = t & 63;
    int w = t >> 6;
    int m0 = w * 16;
    int g = lane >> 3;           // group 0..7
    uint p = (uint)(lane & 7);   // uint4 index (dims 8p..8p+7)

#pragma unroll
    for (int s = 0; s < 2; s++) {
        int row = m0 + 8 * s + g;
        int v = node0 + row;
        if (v < n) {
            f32x2 c0 = {0.f, 0.f}, c1 = {0.f, 0.f}, c2 = {0.f, 0.f}, c3 = {0.f, 0.f};
            uint4 su = h128[(uint)v * 8u + p];
            ACC4(su);
            int e0r = sRP[row], e1r = sRP[row + 1];
            for (int e = e0r; e < e1r; e += 8) {
                int eo = e - eBase;
                uint k0 = sSrc[eo + 0];
                uint k1 = (e + 1 < e1r) ? (uint)sSrc[eo + 1] : 50000u;
                uint k2 = (e + 2 < e1r) ? (uint)sSrc[eo + 2] : 50000u;
                uint k3 = (e + 3 < e1r) ? (uint)sSrc[eo + 3] : 50000u;
                uint k4 = (e + 4 < e1r) ? (uint)sSrc[eo + 4] : 50000u;
                uint k5 = (e + 5 < e1r) ? (uint)sSrc[eo + 5] : 50000u;
                uint k6 = (e + 6 < e1r) ? (uint)sSrc[eo + 6] : 50000u;
                uint k7 = (e + 7 < e1r) ? (uint)sSrc[eo + 7] : 50000u;
                uint4 v0 = h128[k0 * 8u + p];
                uint4 v1 = h128[k1 * 8u + p];
                uint4 v2 = h128[k2 * 8u + p];
                uint4 v3 = h128[k3 * 8u + p];
                uint4 v4 = h128[k4 * 8u + p];
                uint4 v5 = h128[k5 * 8u + p];
                uint4 v6 = h128[k6 * 8u + p];
                uint4 v7 = h128[k7 * 8u + p];
                ACC4(v0); ACC4(v1); ACC4(v2); ACC4(v3);
                ACC4(v4); ACC4(v5); ACC4(v6); ACC4(v7);
            }
            uint4 o;
            o.x = f2bf(c0.x) | (f2bf(c0.y) << 16);
            o.y = f2bf(c1.x) | (f2bf(c1.y) << 16);
            o.z = f2bf(c2.x) | (f2bf(c2.y) << 16);
            o.w = f2bf(c3.x) | (f2bf(c3.y) << 16);
            *(uint4*)&sX[row * LSTR + (int)p * 8] = o;
        }
    }
    // no barrier: rows m0..m0+15 are wave-private from here on

    // ---- MFMA MLP (layouts verified learn_hip m89/m91)
    int mc = lane & 15;
    int quad = lane >> 4;

    bf16x8 xa0 = *(const bf16x8*)&sX[(m0 + mc) * LSTR + quad * 8];
    bf16x8 xa1 = *(const bf16x8*)&sX[(m0 + mc) * LSTR + 32 + quad * 8];
    ushort hreg[16];
#pragma unroll
    for (int c = 0; c < 4; c++) {
        bf16x8 b0 = *(const bf16x8*)&sW1[(c * 16 + mc) * LSTR + quad * 8];
        bf16x8 b1 = *(const bf16x8*)&sW1[(c * 16 + mc) * LSTR + 32 + quad * 8];
        f32x4 acc = {0.f, 0.f, 0.f, 0.f};
        acc = __builtin_amdgcn_mfma_f32_16x16x32_bf16(xa0, b0, acc, 0, 0, 0);
        acc = __builtin_amdgcn_mfma_f32_16x16x32_bf16(xa1, b1, acc, 0, 0, 0);
        int col = c * 16 + mc;
        float bias = sba[col];
#pragma unroll
        for (int r = 0; r < 4; r++)
            hreg[c * 4 + r] = (ushort)f2bf(fmaxf(acc[r] + bias, 0.f));
    }
#pragma unroll
    for (int c = 0; c < 4; c++) {
        int col = c * 16 + mc;
#pragma unroll
        for (int r = 0; r < 4; r++)
            sX[(m0 + quad * 4 + r) * LSTR + col] = hreg[c * 4 + r];
    }

    bool rok[4];
#pragma unroll
    for (int r = 0; r < 4; r++) rok[r] = (node0 + m0 + quad * 4 + r) < n;
    float csum[4] = {0.f, 0.f, 0.f, 0.f};

    bf16x8 ha0 = *(const bf16x8*)&sX[(m0 + mc) * LSTR + quad * 8];
    bf16x8 ha1 = *(const bf16x8*)&sX[(m0 + mc) * LSTR + 32 + quad * 8];
#pragma unroll
    for (int c = 0; c < 4; c++) {
        bf16x8 b0 = *(const bf16x8*)&sW2[(c * 16 + mc) * LSTR + quad * 8];
        bf16x8 b1 = *(const bf16x8*)&sW2[(c * 16 + mc) * LSTR + 32 + quad * 8];
        f32x4 acc = {0.f, 0.f, 0.f, 0.f};
        acc = __builtin_amdgcn_mfma_f32_16x16x32_bf16(ha0, b0, acc, 0, 0, 0);
        acc = __builtin_amdgcn_mfma_f32_16x16x32_bf16(ha1, b1, acc, 0, 0, 0);
        int col = c * 16 + mc;
        float bias = sbb[col];
#pragma unroll
        for (int r = 0; r < 4; r++) {
            float val = acc[r] + bias;
            hreg[c * 4 + r] = (ushort)f2bf(val);
            csum[c] += rok[r] ? val : 0.f;   // NaN-safe masking (select, not mul)
        }
    }
#pragma unroll
    for (int c = 0; c < 4; c++) {
        int col = c * 16 + mc;
#pragma unroll
        for (int r = 0; r < 4; r++)
            sX[(m0 + quad * 4 + r) * LSTR + col] = hreg[c * 4 + r];
    }

    // output: wave-private rows, 2 x uint4 per lane
#pragma unroll
    for (int i = 0; i < 2; i++) {
        int idx = i * 64 + lane;          // 0..127
        int row16 = idx >> 3, q = idx & 7;
        int row = m0 + row16;
        int gr = node0 + row;
        if (gr < n) out128[(size_t)gr * 8 + q] = *(const uint4*)&sX[row * LSTR + q * 8];
    }

    // ---- fused mean-pool partial + last-block final linear (layer 3 only)
    if (part) {
#pragma unroll
        for (int c = 0; c < 4; c++) {
            csum[c] += __shfl_xor(csum[c], 16);
            csum[c] += __shfl_xor(csum[c], 32);
        }
        if (quad == 0) {
#pragma unroll
            for (int c = 0; c < 4; c++) pool[w * 64 + c * 16 + mc] = csum[c];
        }
        __syncthreads();
        if (t < 64) {
            float s4 = pool[t] + pool[64 + t] + pool[128 + t] + pool[192 + t];
            atomicAdd(&part[t], s4);
        }
        __syncthreads();   // drains vmcnt: this block's part atomics performed
        if (t == 0) {
            __threadfence();
            int old = atomicAdd(ticket, 1);
            lastFlag = (old == NB64 - 1) ? 1 : 0;
        }
        __syncthreads();
        if (lastFlag) {
            // last block: all other blocks' part atomics are performed (they
            // precede their ticket add). Agent-scope atomic loads read the
            // coherent copy regardless of this XCD's L2 state.
            if (t < 64)
                pool[t] = __hip_atomic_load(&part[t], __ATOMIC_RELAXED,
                                            __HIP_MEMORY_SCOPE_AGENT) * (1.0f / (float)NNODES);
            __syncthreads();
            if (t < DOUT) {
                float o = bout[t];
                for (int d = 0; d < DDIM; d++) o += pool[d] * Wout[d * DOUT + t];
                out[t] = o;
            }
        }
    }
}

// ---------------- launch ----------------

extern "C" void kernel_launch(void* const* d_in, const int* in_sizes, int n_in,
                              void* d_out, int out_size, void* d_ws, size_t ws_size,
                              hipStream_t stream) {
    const float* features = (const float*)d_in[0];
    const int*   src      = (const int*)d_in[1];
    const int*   dst      = (const int*)d_in[2];
    const float* W0a = (const float*)d_in[3];  const float* b0a = (const float*)d_in[4];
    const float* W0b = (const float*)d_in[5];  const float* b0b = (const float*)d_in[6];
    const float* W1a = (const float*)d_in[7];  const float* b1a = (const float*)d_in[8];
    const float* W1b = (const float*)d_in[9];  const float* b1b = (const float*)d_in[10];
    const float* W2a = (const float*)d_in[11]; const float* b2a = (const float*)d_in[12];
    const float* W2b = (const float*)d_in[13]; const float* b2b = (const float*)d_in[14];
    const float* Wout = (const float*)d_in[15]; const float* bout = (const float*)d_in[16];
    float* out = (float*)d_out;

    // workspace layout (16B-aligned segments)
    int* gh     = (int*)d_ws;                // [38416]
    int* rowptr = gh + 38416;                // [50001] -> pad 50016
    uint* keybuf = (uint*)(rowptr + 50016);  // [800000] (final sorted edge list)
    uint* buf2   = keybuf + 800000;          // [800000] (pass-1 partitioned)
    uint* hb0    = buf2 + 800000;            // bf16 h ping [(50000+1)*32]
    uint* hb1    = hb0 + (NNODES + 1) * 32;  // bf16 h pong
    float* part  = (float*)(hb1 + (NNODES + 1) * 32); // [64]
    int* ticket  = (int*)(part + 64);        // [1] -> pad 4
    uint* wWT    = (uint*)(ticket + 4);      // 6 x 2048 packed bf16 W^T

    // S1: keys+hist | feature cvt | weight cvt | misc zero (196+1024+6+1 blocks)
    s1_kernel<<<NB1 + CVTB + 7, 256, 0, stream>>>(src, dst, keybuf, gh,
                                                  (const float2*)features, hb0, hb1,
                                                  W0a, W0b, W1a, W1b, W2a, W2b,
                                                  wWT, part, ticket);
    sort_scatter1_kernel<<<NB1, 256, 0, stream>>>(keybuf, gh, buf2);
    sort_bucket_kernel<<<NBUCK, 256, 0, stream>>>(buf2, gh, rowptr, keybuf);

    // 3 fused GIN layers (last one also pools + last block computes final linear)
    gin_layer_kernel<<<NB64, 256, 0, stream>>>((const uint4*)hb0, rowptr, keybuf,
                                               (const uint4*)(wWT + 0 * 2048),
                                               (const uint4*)(wWT + 1 * 2048),
                                               b0a, b0b, (uint4*)hb1,
                                               nullptr, nullptr, nullptr, nullptr, nullptr, NNODES);
    gin_layer_kernel<<<NB64, 256, 0, stream>>>((const uint4*)hb1, rowptr, keybuf,
                                               (const uint4*)(wWT + 2 * 2048),
                                               (const uint4*)(wWT + 3 * 2048),
                                               b1a, b1b, (uint4*)hb0,
                                               nullptr, nullptr, nullptr, nullptr, nullptr, NNODES);
    gin_layer_kernel<<<NB64, 256, 0, stream>>>((const uint4*)hb0, rowptr, keybuf,
                                               (const uint4*)(wWT + 4 * 2048),
                                               (const uint4*)(wWT + 5 * 2048),
                                               b2a, b2b, (uint4*)hb1,
                                               part, ticket, Wout, bout, out, NNODES);
}

// Round 4
// 200.384 us; speedup vs baseline: 1.1447x; 1.1447x over previous
//
#include <hip/hip_runtime.h>
#include <hip/hip_bf16.h>

// GIN: 3x [agg = segment_sum(h[src], dst); r = h + agg; h = relu(r@Wa+ba)@Wb+bb]
// then mean over nodes @ Wout + bout -> [1,16]
//
// R15 (from R14 @ 229us, regressed vs R12 @ 199us):
//  - sort chain reverted to R12 structure: sort_offsets_a restored (R14's
//    in-block gh recompute cost ~10-15us/kernel on 1-block/CU grids).
//  - gin blocks: 256 -> 512 threads (8 waves). Each 8-lane group owns ONE row
//    (was 2 sequential): per-wave gather critical path halves, waves/CU 12->24
//    (counters showed latency-bound: occ 20.7%, HBM 13.5%, VALU 11.5%).
//    One __syncthreads() after gather; waves 0-3 run the MFMA/output path.
//  - kept from R14: weight pre-cvt to bf16 (s1), granularized feature cvt,
//    parallel S4 scan, last-block ticket final linear.

#define NNODES 50000
#define NEDGES 800000
#define DDIM   64
#define DOUT   16

#define CHUNK  4096
#define NB1    196           // ceil(800000/4096) sort chunks
#define NBUCK  196           // ceil(50000/256), bucket = dst>>8
#define NB64   782           // ceil(50000/64) gin blocks
#define CVTB   1024          // feature-cvt blocks (grid-stride)

#define KCAP   1408          // staged edges/block (mean 1024, sigma~32; +12 sigma)

typedef unsigned int uint;
typedef unsigned short ushort;
typedef __attribute__((ext_vector_type(8))) short bf16x8;
typedef __attribute__((ext_vector_type(4))) float f32x4;
typedef __attribute__((ext_vector_type(2))) float f32x2;

#define LSTR 72   // LDS row stride in ushorts (144B rows, 16B-aligned)

// fp32 -> bf16 RNE (bit trick)
static __device__ __forceinline__ uint f2bf(float f) {
    uint u = __float_as_uint(f);
    return (u + 0x7fffu + ((u >> 16) & 1u)) >> 16;
}
static __device__ __forceinline__ float bf_lo(uint u) { return __uint_as_float(u << 16); }
static __device__ __forceinline__ float bf_hi(uint u) { return __uint_as_float(u & 0xffff0000u); }

#define ACC4(vv) do { f32x2 u_;                                   \
    u_.x = bf_lo((vv).x); u_.y = bf_hi((vv).x); c0 += u_;         \
    u_.x = bf_lo((vv).y); u_.y = bf_hi((vv).y); c1 += u_;         \
    u_.x = bf_lo((vv).z); u_.y = bf_hi((vv).z); c2 += u_;         \
    u_.x = bf_lo((vv).w); u_.y = bf_hi((vv).w); c3 += u_; } while (0)

// ---------------- S1: keypack+hist | feature cvt | weight cvt | misc zero ----------------

__global__ __launch_bounds__(256) void s1_kernel(const int* __restrict__ src,
                                                 const int* __restrict__ dst,
                                                 uint* __restrict__ key,
                                                 int* __restrict__ gh,
                                                 const float2* __restrict__ fin,
                                                 uint* __restrict__ hb0,
                                                 uint* __restrict__ hb1,
                                                 const float* __restrict__ Wa0,
                                                 const float* __restrict__ Wb0,
                                                 const float* __restrict__ Wa1,
                                                 const float* __restrict__ Wb1,
                                                 const float* __restrict__ Wa2,
                                                 const float* __restrict__ Wb2,
                                                 uint* __restrict__ wWT,
                                                 float* __restrict__ part,
                                                 int* __restrict__ ticket) {
    __shared__ int h[NBUCK];
    int blk = blockIdx.x;
    int t = threadIdx.x;
    if (blk < NB1) {
        for (int i = t; i < NBUCK; i += 256) h[i] = 0;
        __syncthreads();
        int base = blk * CHUNK;
        int end = base + CHUNK < NEDGES ? base + CHUNK : NEDGES;
        for (int i = base + t; i < end; i += 256) {
            int d = dst[i];
            key[i] = ((uint)d << 16) | (uint)src[i];
            atomicAdd(&h[d >> 8], 1);
        }
        __syncthreads();
        for (int i = t; i < NBUCK; i += 256) gh[blk * NBUCK + i] = h[i];
        return;
    }
    int m = blk - NB1;
    if (m < CVTB) {
        // feature cvt (fp32 -> packed bf16), includes dummy row NNODES (zeroed)
        for (int i = m * 256 + t; i < (NNODES + 1) * 32; i += CVTB * 256) {
            uint r = 0u;
            if (i < NNODES * 32) {
                float2 v = fin[i];
                r = f2bf(v.x) | (f2bf(v.y) << 16);
            }
            hb0[i] = r;
        }
        return;
    }
    m -= CVTB;
    if (m < 6) {
        // weight cvt+transpose: wWT[m] as ushort[nn*64 + k] = bf16(W[k][nn])
        const float* Wm = (m == 0) ? Wa0 : (m == 1) ? Wb0 : (m == 2) ? Wa1
                        : (m == 3) ? Wb1 : (m == 4) ? Wa2 : Wb2;
        for (int o = t; o < 2048; o += 256) {
            int nn = o >> 5, kk = o & 31;
            wWT[m * 2048 + o] = f2bf(Wm[(2 * kk) * 64 + nn]) |
                                (f2bf(Wm[(2 * kk + 1) * 64 + nn]) << 16);
        }
        return;
    }
    // misc zeroing block
    if (t < 64) part[t] = 0.f;
    if (t == 64) *ticket = 0;
    if (t >= 128 && t < 160) hb1[NNODES * 32 + (t - 128)] = 0u;   // hb1 dummy row
}

// ---------------- S2a: per-bucket scan over the 196 chunk counts ----------------

__global__ __launch_bounds__(256) void sort_offsets_a_kernel(const int* __restrict__ gh,
                                                             int* __restrict__ offraw,
                                                             int* __restrict__ tot) {
    __shared__ int s[256];
    int b = blockIdx.x;
    int i = threadIdx.x;
    int v = (i < NB1) ? gh[i * NBUCK + b] : 0;
    s[i] = v;
    __syncthreads();
    for (int off = 1; off < 256; off <<= 1) {
        int add = (i >= off) ? s[i - off] : 0;
        __syncthreads();
        s[i] += add;
        __syncthreads();
    }
    if (i < NB1) offraw[i * NBUCK + b] = s[i] - v;   // exclusive within bucket
    if (i == 255) tot[b] = s[255];
}

// ---------------- S3: partition into coarse buckets (bucket bases from tot scan) ----------------

__global__ __launch_bounds__(256) void sort_scatter1_kernel(const uint* __restrict__ key,
                                                            const int* __restrict__ offraw,
                                                            const int* __restrict__ tot,
                                                            uint* __restrict__ out) {
    __shared__ int s[256];
    __shared__ int cur[NBUCK];
    int blk = blockIdx.x;
    int t = threadIdx.x;
    int v = (t < NBUCK) ? tot[t] : 0;
    s[t] = v;
    __syncthreads();
    for (int off = 1; off < 256; off <<= 1) {
        int add = (t >= off) ? s[t - off] : 0;
        __syncthreads();
        s[t] += add;
        __syncthreads();
    }
    if (t < NBUCK) cur[t] = (s[t] - v) + offraw[blk * NBUCK + t];
    __syncthreads();
    int base = blk * CHUNK;
    int end = base + CHUNK < NEDGES ? base + CHUNK : NEDGES;
    for (int j = base + t; j < end; j += 256) {
        uint k = key[j];
        int pos = atomicAdd(&cur[k >> 24], 1);   // k>>24 == dst>>8
        out[pos] = k;
    }
}

// ---------------- S4: per-bucket counting sort by dst&255; emits rowptr ----------------

__global__ __launch_bounds__(256) void sort_bucket_kernel(const uint* __restrict__ in,
                                                          const int* __restrict__ tot,
                                                          int* __restrict__ rowptr,
                                                          uint* __restrict__ out) {
    __shared__ int s[256];
    __shared__ int hh[256];
    __shared__ int cur[256];
    __shared__ int slo[2];
    int blk = blockIdx.x;
    int t = threadIdx.x;
    int v = (t < NBUCK) ? tot[t] : 0;
    s[t] = v;
    __syncthreads();
    for (int off = 1; off < 256; off <<= 1) {
        int add = (t >= off) ? s[t - off] : 0;
        __syncthreads();
        s[t] += add;
        __syncthreads();
    }
    if (t == blk) { slo[0] = s[t] - v; slo[1] = s[t]; }
    hh[t] = 0;
    __syncthreads();
    int lo = slo[0], hi = slo[1];
    for (int i = lo + t; i < hi; i += 256)
        atomicAdd(&hh[(in[i] >> 16) & 255], 1);
    __syncthreads();
    int hv = hh[t];
    s[t] = hv;
    __syncthreads();
    for (int off = 1; off < 256; off <<= 1) {
        int add = (t >= off) ? s[t - off] : 0;
        __syncthreads();
        s[t] += add;
        __syncthreads();
    }
    cur[t] = lo + s[t] - hv;   // exclusive scan + bucket base
    __syncthreads();
    int node = (blk << 8) + t;
    if (node < NNODES) rowptr[node] = cur[t];
    if (blk == NBUCK - 1 && t == 0) rowptr[NNODES] = NEDGES;
    __syncthreads();   // rowptr reads of cur[] before scatter mutates it
    for (int i = lo + t; i < hi; i += 256) {
        uint k = in[i];
        int pos = atomicAdd(&cur[(k >> 16) & 255], 1);
        out[pos] = k;
    }
}

// ---------------- fused GIN layer (512 threads / 8 waves) ----------------
// 64 nodes/block. Gather: 64 groups of 8 lanes, ONE row per group (wave w owns
// rows 8w..8w+7) -> per-wave critical path halves vs 4-wave version, 2x waves
// resident. One barrier after gather; waves 0-3 then run the MFMA MLP on
// 16-row tiles (rows 16w..16w+15), wave-private to the end.

__global__ __launch_bounds__(512, 8) void gin_layer_kernel(const uint4* __restrict__ h128,
                                                           const int* __restrict__ rowptr,
                                                           const uint* __restrict__ skey,
                                                           const uint4* __restrict__ wa4,
                                                           const uint4* __restrict__ wb4,
                                                           const float* __restrict__ ba,
                                                           const float* __restrict__ bb,
                                                           uint4* __restrict__ out128,
                                                           float* __restrict__ part,
                                                           int* __restrict__ ticket,
                                                           const float* __restrict__ Wout,
                                                           const float* __restrict__ bout,
                                                           float* __restrict__ out, int n) {
    __shared__ ushort sW1[64 * LSTR];   // Wa^T bf16 [n][k]
    __shared__ ushort sW2[64 * LSTR];   // Wb^T bf16 [n][k]
    __shared__ ushort sX[64 * LSTR];    // r tile -> hidden tile -> output staging
    __shared__ float sba[64], sbb[64];
    __shared__ ushort sSrc[KCAP + 8];   // staged src indices (+8 slack for masked reads)
    __shared__ int sRP[65];             // staged rowptr[node0..node0+64]
    __shared__ float pool[256];
    __shared__ int lastFlag;

    int t = threadIdx.x;
    int node0 = blockIdx.x * 64;

    for (int i = t; i < 512; i += 512) {
        int nn = i >> 3, k8 = i & 7;
        *(uint4*)&sW1[nn * LSTR + k8 * 8] = wa4[nn * 8 + k8];
        *(uint4*)&sW2[nn * LSTR + k8 * 8] = wb4[nn * 8 + k8];
    }
    if (t < 64) { sba[t] = ba[t]; sbb[t] = bb[t]; }
    if (t >= 64 && t < 129) {
        int idx = node0 + (t - 64);
        sRP[t - 64] = rowptr[idx < n ? idx : n];
    }
    if (blockIdx.x == 0 && t >= 192 && t < 200) {   // zero dummy row of output
        uint4 z; z.x = 0; z.y = 0; z.z = 0; z.w = 0;
        out128[(size_t)NNODES * 8 + (t - 192)] = z;
    }
    int eBase = rowptr[node0];
    int vEnd = node0 + 64 < n ? node0 + 64 : n;
    int nE = rowptr[vEnd] - eBase;
    int nS = nE < KCAP ? nE : KCAP;
    for (int i = t; i < nS; i += 512) sSrc[i] = (ushort)skey[eBase + i];
    __syncthreads();   // weights/keys/rowptr visible

    int lane = t & 63;
    int w = t >> 6;              // wave 0..7
    int g = lane >> 3;           // group 0..7
    uint p = (uint)(lane & 7);   // uint4 index (dims 8p..8p+7)

    {
        int row = w * 8 + g;     // one row per 8-lane group
        int v = node0 + row;
        if (v < n) {
            f32x2 c0 = {0.f, 0.f}, c1 = {0.f, 0.f}, c2 = {0.f, 0.f}, c3 = {0.f, 0.f};
            uint4 su = h128[(uint)v * 8u + p];
            ACC4(su);
            int e0r = sRP[row], e1r = sRP[row + 1];
            for (int e = e0r; e < e1r; e += 8) {
                int eo = e - eBase;
                uint k0 = sSrc[eo + 0];
                uint k1 = (e + 1 < e1r) ? (uint)sSrc[eo + 1] : 50000u;
                uint k2 = (e + 2 < e1r) ? (uint)sSrc[eo + 2] : 50000u;
                uint k3 = (e + 3 < e1r) ? (uint)sSrc[eo + 3] : 50000u;
                uint k4 = (e + 4 < e1r) ? (uint)sSrc[eo + 4] : 50000u;
                uint k5 = (e + 5 < e1r) ? (uint)sSrc[eo + 5] : 50000u;
                uint k6 = (e + 6 < e1r) ? (uint)sSrc[eo + 6] : 50000u;
                uint k7 = (e + 7 < e1r) ? (uint)sSrc[eo + 7] : 50000u;
                uint4 v0 = h128[k0 * 8u + p];
                uint4 v1 = h128[k1 * 8u + p];
                uint4 v2 = h128[k2 * 8u + p];
                uint4 v3 = h128[k3 * 8u + p];
                uint4 v4 = h128[k4 * 8u + p];
                uint4 v5 = h128[k5 * 8u + p];
                uint4 v6 = h128[k6 * 8u + p];
                uint4 v7 = h128[k7 * 8u + p];
                ACC4(v0); ACC4(v1); ACC4(v2); ACC4(v3);
                ACC4(v4); ACC4(v5); ACC4(v6); ACC4(v7);
            }
            uint4 o;
            o.x = f2bf(c0.x) | (f2bf(c0.y) << 16);
            o.y = f2bf(c1.x) | (f2bf(c1.y) << 16);
            o.z = f2bf(c2.x) | (f2bf(c2.y) << 16);
            o.w = f2bf(c3.x) | (f2bf(c3.y) << 16);
            *(uint4*)&sX[row * LSTR + (int)p * 8] = o;
        }
    }
    __syncthreads();   // gather tile complete before MFMA waves read it

    // ---- MFMA MLP on waves 0-3 (layouts verified learn_hip m89/m91)
    int mc = lane & 15;
    int quad = lane >> 4;
    int m0 = w * 16;
    float csum[4] = {0.f, 0.f, 0.f, 0.f};

    if (w < 4) {
        bf16x8 xa0 = *(const bf16x8*)&sX[(m0 + mc) * LSTR + quad * 8];
        bf16x8 xa1 = *(const bf16x8*)&sX[(m0 + mc) * LSTR + 32 + quad * 8];
        ushort hreg[16];
#pragma unroll
        for (int c = 0; c < 4; c++) {
            bf16x8 b0 = *(const bf16x8*)&sW1[(c * 16 + mc) * LSTR + quad * 8];
            bf16x8 b1 = *(const bf16x8*)&sW1[(c * 16 + mc) * LSTR + 32 + quad * 8];
            f32x4 acc = {0.f, 0.f, 0.f, 0.f};
            acc = __builtin_amdgcn_mfma_f32_16x16x32_bf16(xa0, b0, acc, 0, 0, 0);
            acc = __builtin_amdgcn_mfma_f32_16x16x32_bf16(xa1, b1, acc, 0, 0, 0);
            int col = c * 16 + mc;
            float bias = sba[col];
#pragma unroll
            for (int r = 0; r < 4; r++)
                hreg[c * 4 + r] = (ushort)f2bf(fmaxf(acc[r] + bias, 0.f));
        }
#pragma unroll
        for (int c = 0; c < 4; c++) {
            int col = c * 16 + mc;
#pragma unroll
            for (int r = 0; r < 4; r++)
                sX[(m0 + quad * 4 + r) * LSTR + col] = hreg[c * 4 + r];
        }

        bool rok[4];
#pragma unroll
        for (int r = 0; r < 4; r++) rok[r] = (node0 + m0 + quad * 4 + r) < n;

        bf16x8 ha0 = *(const bf16x8*)&sX[(m0 + mc) * LSTR + quad * 8];
        bf16x8 ha1 = *(const bf16x8*)&sX[(m0 + mc) * LSTR + 32 + quad * 8];
#pragma unroll
        for (int c = 0; c < 4; c++) {
            bf16x8 b0 = *(const bf16x8*)&sW2[(c * 16 + mc) * LSTR + quad * 8];
            bf16x8 b1 = *(const bf16x8*)&sW2[(c * 16 + mc) * LSTR + 32 + quad * 8];
            f32x4 acc = {0.f, 0.f, 0.f, 0.f};
            acc = __builtin_amdgcn_mfma_f32_16x16x32_bf16(ha0, b0, acc, 0, 0, 0);
            acc = __builtin_amdgcn_mfma_f32_16x16x32_bf16(ha1, b1, acc, 0, 0, 0);
            int col = c * 16 + mc;
            float bias = sbb[col];
#pragma unroll
            for (int r = 0; r < 4; r++) {
                float val = acc[r] + bias;
                hreg[c * 4 + r] = (ushort)f2bf(val);
                csum[c] += rok[r] ? val : 0.f;   // NaN-safe masking (select, not mul)
            }
        }
#pragma unroll
        for (int c = 0; c < 4; c++) {
            int col = c * 16 + mc;
#pragma unroll
            for (int r = 0; r < 4; r++)
                sX[(m0 + quad * 4 + r) * LSTR + col] = hreg[c * 4 + r];
        }

        // output: wave-private rows, 2 x uint4 per lane
#pragma unroll
        for (int i = 0; i < 2; i++) {
            int idx = i * 64 + lane;          // 0..127
            int row16 = idx >> 3, q = idx & 7;
            int row = m0 + row16;
            int gr = node0 + row;
            if (gr < n) out128[(size_t)gr * 8 + q] = *(const uint4*)&sX[row * LSTR + q * 8];
        }
    }

    // ---- fused mean-pool partial + last-block final linear (layer 3 only)
    if (part) {
        if (w < 4) {
#pragma unroll
            for (int c = 0; c < 4; c++) {
                csum[c] += __shfl_xor(csum[c], 16);
                csum[c] += __shfl_xor(csum[c], 32);
            }
            if (quad == 0) {
#pragma unroll
                for (int c = 0; c < 4; c++) pool[w * 64 + c * 16 + mc] = csum[c];
            }
        }
        __syncthreads();
        if (t < 64) {
            float s4 = pool[t] + pool[64 + t] + pool[128 + t] + pool[192 + t];
            atomicAdd(&part[t], s4);
        }
        __syncthreads();   // this block's part atomics performed
        if (t == 0) {
            __threadfence();
            int old = atomicAdd(ticket, 1);
            lastFlag = (old == NB64 - 1) ? 1 : 0;
        }
        __syncthreads();
        if (lastFlag) {
            // last block: all other blocks' part atomics precede their ticket
            // add. Agent-scope atomic loads read the coherent copy.
            if (t < 64)
                pool[t] = __hip_atomic_load(&part[t], __ATOMIC_RELAXED,
                                            __HIP_MEMORY_SCOPE_AGENT) * (1.0f / (float)NNODES);
            __syncthreads();
            if (t < DOUT) {
                float o = bout[t];
                for (int d = 0; d < DDIM; d++) o += pool[d] * Wout[d * DOUT + t];
                out[t] = o;
            }
        }
    }
}

// ---------------- launch ----------------

extern "C" void kernel_launch(void* const* d_in, const int* in_sizes, int n_in,
                              void* d_out, int out_size, void* d_ws, size_t ws_size,
                              hipStream_t stream) {
    const float* features = (const float*)d_in[0];
    const int*   src      = (const int*)d_in[1];
    const int*   dst      = (const int*)d_in[2];
    const float* W0a = (const float*)d_in[3];  const float* b0a = (const float*)d_in[4];
    const float* W0b = (const float*)d_in[5];  const float* b0b = (const float*)d_in[6];
    const float* W1a = (const float*)d_in[7];  const float* b1a = (const float*)d_in[8];
    const float* W1b = (const float*)d_in[9];  const float* b1b = (const float*)d_in[10];
    const float* W2a = (const float*)d_in[11]; const float* b2a = (const float*)d_in[12];
    const float* W2b = (const float*)d_in[13]; const float* b2b = (const float*)d_in[14];
    const float* Wout = (const float*)d_in[15]; const float* bout = (const float*)d_in[16];
    float* out = (float*)d_out;

    // workspace layout (16B-aligned segments)
    int* gh     = (int*)d_ws;                // [38416]
    int* offraw = gh + 38416;                // [38416]
    int* tot    = offraw + 38416;            // [256]
    int* rowptr = tot + 256;                 // [50001] -> pad 50016
    uint* keybuf = (uint*)(rowptr + 50016);  // [800000] (final sorted edge list)
    uint* buf2   = keybuf + 800000;          // [800000] (pass-1 partitioned)
    uint* hb0    = buf2 + 800000;            // bf16 h ping [(50000+1)*32]
    uint* hb1    = hb0 + (NNODES + 1) * 32;  // bf16 h pong
    float* part  = (float*)(hb1 + (NNODES + 1) * 32); // [64]
    int* ticket  = (int*)(part + 64);        // [1] -> pad 4
    uint* wWT    = (uint*)(ticket + 4);      // 6 x 2048 packed bf16 W^T

    // S1: keys+hist | feature cvt | weight cvt | misc zero
    s1_kernel<<<NB1 + CVTB + 7, 256, 0, stream>>>(src, dst, keybuf, gh,
                                                  (const float2*)features, hb0, hb1,
                                                  W0a, W0b, W1a, W1b, W2a, W2b,
                                                  wWT, part, ticket);
    sort_offsets_a_kernel<<<NBUCK, 256, 0, stream>>>(gh, offraw, tot);
    sort_scatter1_kernel<<<NB1, 256, 0, stream>>>(keybuf, offraw, tot, buf2);
    sort_bucket_kernel<<<NBUCK, 256, 0, stream>>>(buf2, tot, rowptr, keybuf);

    // 3 fused GIN layers (last one also pools + last block computes final linear)
    gin_layer_kernel<<<NB64, 512, 0, stream>>>((const uint4*)hb0, rowptr, keybuf,
                                               (const uint4*)(wWT + 0 * 2048),
                                               (const uint4*)(wWT + 1 * 2048),
                                               b0a, b0b, (uint4*)hb1,
                                               nullptr, nullptr, nullptr, nullptr, nullptr, NNODES);
    gin_layer_kernel<<<NB64, 512, 0, stream>>>((const uint4*)hb1, rowptr, keybuf,
                                               (const uint4*)(wWT + 2 * 2048),
                                               (const uint4*)(wWT + 3 * 2048),
                                               b1a, b1b, (uint4*)hb0,
                                               nullptr, nullptr, nullptr, nullptr, nullptr, NNODES);
    gin_layer_kernel<<<NB64, 512, 0, stream>>>((const uint4*)hb0, rowptr, keybuf,
                                               (const uint4*)(wWT + 4 * 2048),
                                               (const uint4*)(wWT + 5 * 2048),
                                               b2a, b2b, (uint4*)hb1,
                                               part, ticket, Wout, bout, out, NNODES);
}